// Round 4
// baseline (1275.128 us; speedup 1.0000x reference)
//
#include <hip/hip_runtime.h>
#include <cstddef>

#define NN 100000
#define NE 1600000
#define NBLK 98   // ceil(NN / 1024)

// ===========================================================================
// CSR build: histogram(dst) -> hierarchical exclusive scan -> scatter
// ===========================================================================
__global__ __launch_bounds__(256) void hist_dst(const int* __restrict__ ei,
                                                int* __restrict__ deg)
{
    int i = blockIdx.x * 256 + threadIdx.x;
    int stride = gridDim.x * 256;
    for (int e = i; e < NE; e += stride)
        atomicAdd(&deg[ei[NE + e]], 1);
}

// Stage 1: per-block (1024 elems) sum of degrees
__global__ __launch_bounds__(1024) void deg_block_sum(const int* __restrict__ deg,
                                                      int* __restrict__ bsum)
{
    __shared__ int s[16];
    int t = threadIdx.x;
    int i = blockIdx.x * 1024 + t;
    int v = (i < NN) ? deg[i] : 0;
    #pragma unroll
    for (int o = 32; o > 0; o >>= 1) v += __shfl_down(v, o, 64);
    if ((t & 63) == 0) s[t >> 6] = v;
    __syncthreads();
    if (t < 64) {
        int w = (t < 16) ? s[t] : 0;
        #pragma unroll
        for (int o = 8; o > 0; o >>= 1) w += __shfl_down(w, o, 64);
        if (t == 0) bsum[blockIdx.x] = w;
    }
}

// Stage 2: exclusive scan of the 98 block sums (single tiny block);
// also writes off[NN] = total edge count.
__global__ __launch_bounds__(128) void scan_bsum(int* __restrict__ bsum,
                                                 int* __restrict__ off)
{
    __shared__ int s[128];
    int t = threadIdx.x;
    int v = (t < NBLK) ? bsum[t] : 0;
    s[t] = v;
    __syncthreads();
    #pragma unroll
    for (int o = 1; o < 128; o <<= 1) {
        int u = (t >= o) ? s[t - o] : 0;
        __syncthreads();
        s[t] += u;
        __syncthreads();
    }
    if (t < NBLK) bsum[t] = s[t] - v;   // exclusive block offset
    if (t == 127) off[NN] = s[127];     // grand total
}

// Stage 3: per-block exclusive scan + block offset. Writes off[i] and
// rewrites deg[i] = off[i] (deg then serves as the scatter cursor).
__global__ __launch_bounds__(1024) void deg_block_scan(int* __restrict__ deg,
                                                       int* __restrict__ off,
                                                       const int* __restrict__ bsum)
{
    __shared__ int s[1024];
    int t = threadIdx.x;
    int i = blockIdx.x * 1024 + t;
    int v = (i < NN) ? deg[i] : 0;
    s[t] = v;
    __syncthreads();
    #pragma unroll
    for (int o = 1; o < 1024; o <<= 1) {
        int u = (t >= o) ? s[t - o] : 0;
        __syncthreads();
        s[t] += u;
        __syncthreads();
    }
    int excl = s[t] - v + bsum[blockIdx.x];
    if (i < NN) { off[i] = excl; deg[i] = excl; }
}

__global__ __launch_bounds__(256) void scatter_perm(const int* __restrict__ ei,
                                                    int* __restrict__ cur,
                                                    int2* __restrict__ perm2)
{
    int i = blockIdx.x * 256 + threadIdx.x;
    int stride = gridDim.x * 256;
    for (int e = i; e < NE; e += stride) {
        int s = ei[e];
        int d = ei[NE + e];
        int pos = atomicAdd(&cur[d], 1);
        perm2[pos] = make_int2(e, s);
    }
}

// ===========================================================================
// conv1 gather: one FULL wave per node, 2 channels/lane (128 ch).
// ALL in-loop memory traffic on the VECTOR path (vmcnt counted waits):
//  - edge records loaded cooperatively (perm2[j0+lane], 1 load per 64 edges)
//  - per-edge (e,s) extracted via __shfl (ds_bpermute) => result is NOT
//    provably uniform, so the compiler CANNOT scalarize the attr loads.
//    (Rounds 0-3 fed attrs through s_load: SMEM is out-of-order => every
//    consumer drains lgkmcnt(0) killing the pipeline, and scalar K$ has
//    shallow miss concurrency on 1.6M random 64B rows => ~200us floor.)
//  - attr rows: per-lane float4 loads at wave-uniform address (TCP broadcast)
// Weights stay register-resident (VALU reads AGPRs directly on gfx950).
// 2-edge ping-pong pipeline, no rotate moves.
// aggr1[n] = sum_{e: dst=n} relu(x[src_e] + ea[e] @ We1 + be1)
// ===========================================================================
__global__ __launch_bounds__(256, 4) void conv1_gather(
    const float* __restrict__ x, const float* __restrict__ ea,
    const float* __restrict__ We, const float* __restrict__ be,
    const int* __restrict__ off, const int2* __restrict__ perm2,
    float* __restrict__ aggr)
{
    int t = threadIdx.x;
    int lane = t & 63;
    int n = blockIdx.x * 4 + (t >> 6);
    if (n >= NN) return;

    // per-lane weight column pair: rw[k] = We[k][2*lane .. 2*lane+1]
    const float2* W2 = (const float2*)We;
    float2 rw[16];
    #pragma unroll
    for (int k = 0; k < 16; k++) rw[k] = W2[(k << 6) + lane];
    float2 bias = ((const float2*)be)[lane];

    int j0 = off[n], j1 = off[n + 1];
    float2 acc = make_float2(0.f, 0.f);

    for (int base = j0; base < j1; base += 64) {
        int last = j1 - 1;
        int cnt = min(64, j1 - base);
        // cooperative record load: lane i holds record base+i (clamped)
        int2 rec = perm2[min(base + lane, last)];

        // prologue: edges 0 and 1 (clamped)
        int i1 = min(1, cnt - 1);
        int eA = __shfl(rec.x, 0),  sA = __shfl(rec.y, 0);
        int eB = __shfl(rec.x, i1), sB = __shfl(rec.y, i1);
        const float4* pA = (const float4*)((const char*)ea + ((size_t)(unsigned)eA << 6));
        const float4* pB = (const float4*)((const char*)ea + ((size_t)(unsigned)eB << 6));
        float4 A0 = pA[0], A1 = pA[1], A2 = pA[2], A3 = pA[3];
        float4 B0 = pB[0], B1 = pB[1], B2 = pB[2], B3 = pB[3];
        float2 xA = *(const float2*)((const char*)x + ((size_t)(unsigned)sA << 9) + (lane << 3));
        float2 xB = *(const float2*)((const char*)x + ((size_t)(unsigned)sB << 9) + (lane << 3));

        for (int i = 0; i < cnt; i += 2) {
            // extract records for edges i+2, i+3 (clamped; redundant loads
            // at the tail hit the same cache line - harmless)
            int i2 = min(i + 2, cnt - 1), i3 = min(i + 3, cnt - 1);
            int eC = __shfl(rec.x, i2), sC = __shfl(rec.y, i2);
            int eD = __shfl(rec.x, i3), sD = __shfl(rec.y, i3);

            // ---- compute edge i (stage A) ----
            {
                float av[16] = {A0.x,A0.y,A0.z,A0.w, A1.x,A1.y,A1.z,A1.w,
                                A2.x,A2.y,A2.z,A2.w, A3.x,A3.y,A3.z,A3.w};
                float2 m = bias;
                #pragma unroll
                for (int k = 0; k < 16; k++) {
                    m.x = fmaf(av[k], rw[k].x, m.x);
                    m.y = fmaf(av[k], rw[k].y, m.y);
                }
                acc.x += fmaxf(xA.x + m.x, 0.0f);
                acc.y += fmaxf(xA.y + m.y, 0.0f);
            }
            // ---- refill stage A <- edge i+2 ----
            {
                const float4* p = (const float4*)((const char*)ea + ((size_t)(unsigned)eC << 6));
                A0 = p[0]; A1 = p[1]; A2 = p[2]; A3 = p[3];
                xA = *(const float2*)((const char*)x + ((size_t)(unsigned)sC << 9) + (lane << 3));
            }
            // ---- compute edge i+1 (stage B), wave-uniform tail guard ----
            if (i + 1 < cnt) {
                float bv[16] = {B0.x,B0.y,B0.z,B0.w, B1.x,B1.y,B1.z,B1.w,
                                B2.x,B2.y,B2.z,B2.w, B3.x,B3.y,B3.z,B3.w};
                float2 m = bias;
                #pragma unroll
                for (int k = 0; k < 16; k++) {
                    m.x = fmaf(bv[k], rw[k].x, m.x);
                    m.y = fmaf(bv[k], rw[k].y, m.y);
                }
                acc.x += fmaxf(xB.x + m.x, 0.0f);
                acc.y += fmaxf(xB.y + m.y, 0.0f);
            }
            // ---- refill stage B <- edge i+3 ----
            {
                const float4* p = (const float4*)((const char*)ea + ((size_t)(unsigned)eD << 6));
                B0 = p[0]; B1 = p[1]; B2 = p[2]; B3 = p[3];
                xB = *(const float2*)((const char*)x + ((size_t)(unsigned)sD << 9) + (lane << 3));
            }
        }
    }
    *(float2*)(aggr + (size_t)n * 128 + (lane << 1)) = acc;
}

// ===========================================================================
// conv_mu + conv_logstd gather, fused: one FULL wave per node. Trees split
// across the wave: lanes 0-31 = mu (W2), lanes 32-63 = logstd (W3),
// 2 channels/lane. Same all-vector-path structure as conv1_gather.
// ===========================================================================
__global__ __launch_bounds__(256, 4) void conv23_gather(
    const float* __restrict__ h, const float* __restrict__ ea,
    const float* __restrict__ We2, const float* __restrict__ be2,
    const float* __restrict__ We3, const float* __restrict__ be3,
    const int* __restrict__ off, const int2* __restrict__ perm2,
    float* __restrict__ aggr2, float* __restrict__ aggr3)
{
    int t = threadIdx.x;
    int lane = t & 63;
    int half = lane >> 5;            // 0 = mu tree, 1 = logstd tree
    int cl = lane & 31;
    int co = cl << 1;                // channel pair within the tree
    int n = blockIdx.x * 4 + (t >> 6);
    if (n >= NN) return;

    const float2* Wp = (const float2*)(half ? We3 : We2);
    const float2* bp = (const float2*)(half ? be3 : be2);
    float2 rw[16];
    #pragma unroll
    for (int k = 0; k < 16; k++) rw[k] = Wp[(k << 5) + cl];
    float2 bias = bp[cl];

    int j0 = off[n], j1 = off[n + 1];
    float2 acc = make_float2(0.f, 0.f);

    for (int base = j0; base < j1; base += 64) {
        int last = j1 - 1;
        int cnt = min(64, j1 - base);
        int2 rec = perm2[min(base + lane, last)];

        int i1 = min(1, cnt - 1);
        int eA = __shfl(rec.x, 0),  sA = __shfl(rec.y, 0);
        int eB = __shfl(rec.x, i1), sB = __shfl(rec.y, i1);
        const float4* pA = (const float4*)((const char*)ea + ((size_t)(unsigned)eA << 6));
        const float4* pB = (const float4*)((const char*)ea + ((size_t)(unsigned)eB << 6));
        float4 A0 = pA[0], A1 = pA[1], A2 = pA[2], A3 = pA[3];
        float4 B0 = pB[0], B1 = pB[1], B2 = pB[2], B3 = pB[3];
        float2 hA = *(const float2*)((const char*)h + ((size_t)(unsigned)sA << 8) + (co << 2));
        float2 hB = *(const float2*)((const char*)h + ((size_t)(unsigned)sB << 8) + (co << 2));

        for (int i = 0; i < cnt; i += 2) {
            int i2 = min(i + 2, cnt - 1), i3 = min(i + 3, cnt - 1);
            int eC = __shfl(rec.x, i2), sC = __shfl(rec.y, i2);
            int eD = __shfl(rec.x, i3), sD = __shfl(rec.y, i3);

            {
                float av[16] = {A0.x,A0.y,A0.z,A0.w, A1.x,A1.y,A1.z,A1.w,
                                A2.x,A2.y,A2.z,A2.w, A3.x,A3.y,A3.z,A3.w};
                float2 m = bias;
                #pragma unroll
                for (int k = 0; k < 16; k++) {
                    m.x = fmaf(av[k], rw[k].x, m.x);
                    m.y = fmaf(av[k], rw[k].y, m.y);
                }
                acc.x += fmaxf(hA.x + m.x, 0.0f);
                acc.y += fmaxf(hA.y + m.y, 0.0f);
            }
            {
                const float4* p = (const float4*)((const char*)ea + ((size_t)(unsigned)eC << 6));
                A0 = p[0]; A1 = p[1]; A2 = p[2]; A3 = p[3];
                hA = *(const float2*)((const char*)h + ((size_t)(unsigned)sC << 8) + (co << 2));
            }
            if (i + 1 < cnt) {
                float bv[16] = {B0.x,B0.y,B0.z,B0.w, B1.x,B1.y,B1.z,B1.w,
                                B2.x,B2.y,B2.z,B2.w, B3.x,B3.y,B3.z,B3.w};
                float2 m = bias;
                #pragma unroll
                for (int k = 0; k < 16; k++) {
                    m.x = fmaf(bv[k], rw[k].x, m.x);
                    m.y = fmaf(bv[k], rw[k].y, m.y);
                }
                acc.x += fmaxf(hB.x + m.x, 0.0f);
                acc.y += fmaxf(hB.y + m.y, 0.0f);
            }
            {
                const float4* p = (const float4*)((const char*)ea + ((size_t)(unsigned)eD << 6));
                B0 = p[0]; B1 = p[1]; B2 = p[2]; B3 = p[3];
                hB = *(const float2*)((const char*)h + ((size_t)(unsigned)sD << 8) + (co << 2));
            }
        }
    }
    float* dstp = (half ? aggr3 : aggr2) + (size_t)n * 64 + co;
    *(float2*)dstp = acc;
}

// ===========================================================================
// Node MLP: out = epilogue( relu((xin+aggr) @ Wa + ba) @ Wb + bb )
// KIN -> 64 -> 64. 64 nodes per block, 256 threads, 4x4 register tiles.
// mode: 0 = none, 1 = relu, 2 = clip(-10, 10)
// ===========================================================================
template <int KIN>
__global__ __launch_bounds__(256) void node_mlp(
    const float* __restrict__ xin, const float* __restrict__ aggr,
    const float* __restrict__ Wa, const float* __restrict__ ba,
    const float* __restrict__ Wb, const float* __restrict__ bb,
    float* __restrict__ out, int mode)
{
    constexpr int S0 = KIN + 4;
    constexpr int K4 = KIN / 4;
    __shared__ float sWa[KIN * 64];
    __shared__ float sWb[64 * 64];
    __shared__ float sh[64 * S0];
    __shared__ float sba[64], sbb[64];
    int t = threadIdx.x;
    for (int i = t; i < KIN * 16; i += 256) ((float4*)sWa)[i] = ((const float4*)Wa)[i];
    for (int i = t; i < 1024; i += 256)     ((float4*)sWb)[i] = ((const float4*)Wb)[i];
    if (t < 64) { sba[t] = ba[t]; sbb[t] = bb[t]; }

    int nb = blockIdx.x << 6;
    for (int i = t; i < 64 * K4; i += 256) {
        int n = i / K4, k4 = i % K4;
        int node = nb + n;
        float4 v = make_float4(0.f, 0.f, 0.f, 0.f);
        if (node < NN) {
            float4 a = ((const float4*)(xin  + (size_t)node * KIN))[k4];
            float4 b = ((const float4*)(aggr + (size_t)node * KIN))[k4];
            v = make_float4(a.x + b.x, a.y + b.y, a.z + b.z, a.w + b.w);
        }
        *(float4*)&sh[n * S0 + (k4 << 2)] = v;
    }
    __syncthreads();

    int tx = t & 15, ty = t >> 4;
    int c0 = tx << 2, n0 = ty << 2;

    float4 b1 = *(const float4*)&sba[c0];
    float acc[4][4];
    #pragma unroll
    for (int i = 0; i < 4; i++) { acc[i][0] = b1.x; acc[i][1] = b1.y; acc[i][2] = b1.z; acc[i][3] = b1.w; }
    for (int k4 = 0; k4 < K4; k4++) {
        int k = k4 << 2;
        float4 w0 = *(const float4*)&sWa[((k + 0) << 6) + c0];
        float4 w1 = *(const float4*)&sWa[((k + 1) << 6) + c0];
        float4 w2 = *(const float4*)&sWa[((k + 2) << 6) + c0];
        float4 w3 = *(const float4*)&sWa[((k + 3) << 6) + c0];
        #pragma unroll
        for (int i = 0; i < 4; i++) {
            float4 hv = *(const float4*)&sh[(n0 + i) * S0 + k];
            acc[i][0] = fmaf(hv.x, w0.x, acc[i][0]); acc[i][1] = fmaf(hv.x, w0.y, acc[i][1]);
            acc[i][2] = fmaf(hv.x, w0.z, acc[i][2]); acc[i][3] = fmaf(hv.x, w0.w, acc[i][3]);
            acc[i][0] = fmaf(hv.y, w1.x, acc[i][0]); acc[i][1] = fmaf(hv.y, w1.y, acc[i][1]);
            acc[i][2] = fmaf(hv.y, w1.z, acc[i][2]); acc[i][3] = fmaf(hv.y, w1.w, acc[i][3]);
            acc[i][0] = fmaf(hv.z, w2.x, acc[i][0]); acc[i][1] = fmaf(hv.z, w2.y, acc[i][1]);
            acc[i][2] = fmaf(hv.z, w2.z, acc[i][2]); acc[i][3] = fmaf(hv.z, w2.w, acc[i][3]);
            acc[i][0] = fmaf(hv.w, w3.x, acc[i][0]); acc[i][1] = fmaf(hv.w, w3.y, acc[i][1]);
            acc[i][2] = fmaf(hv.w, w3.z, acc[i][2]); acc[i][3] = fmaf(hv.w, w3.w, acc[i][3]);
        }
    }
    __syncthreads();
    #pragma unroll
    for (int i = 0; i < 4; i++) {
        float4 v = make_float4(fmaxf(acc[i][0], 0.f), fmaxf(acc[i][1], 0.f),
                               fmaxf(acc[i][2], 0.f), fmaxf(acc[i][3], 0.f));
        *(float4*)&sh[(n0 + i) * 68 + c0] = v;
    }
    __syncthreads();

    float4 b2 = *(const float4*)&sbb[c0];
    float acc2[4][4];
    #pragma unroll
    for (int i = 0; i < 4; i++) { acc2[i][0] = b2.x; acc2[i][1] = b2.y; acc2[i][2] = b2.z; acc2[i][3] = b2.w; }
    for (int k4 = 0; k4 < 16; k4++) {
        int k = k4 << 2;
        float4 w0 = *(const float4*)&sWb[((k + 0) << 6) + c0];
        float4 w1 = *(const float4*)&sWb[((k + 1) << 6) + c0];
        float4 w2 = *(const float4*)&sWb[((k + 2) << 6) + c0];
        float4 w3 = *(const float4*)&sWb[((k + 3) << 6) + c0];
        #pragma unroll
        for (int i = 0; i < 4; i++) {
            float4 hv = *(const float4*)&sh[(n0 + i) * 68 + k];
            acc2[i][0] = fmaf(hv.x, w0.x, acc2[i][0]); acc2[i][1] = fmaf(hv.x, w0.y, acc2[i][1]);
            acc2[i][2] = fmaf(hv.x, w0.z, acc2[i][2]); acc2[i][3] = fmaf(hv.x, w0.w, acc2[i][3]);
            acc2[i][0] = fmaf(hv.y, w1.x, acc2[i][0]); acc2[i][1] = fmaf(hv.y, w1.y, acc2[i][1]);
            acc2[i][2] = fmaf(hv.y, w1.z, acc2[i][2]); acc2[i][3] = fmaf(hv.y, w1.w, acc2[i][3]);
            acc2[i][0] = fmaf(hv.z, w2.x, acc2[i][0]); acc2[i][1] = fmaf(hv.z, w2.y, acc2[i][1]);
            acc2[i][2] = fmaf(hv.z, w2.z, acc2[i][2]); acc2[i][3] = fmaf(hv.z, w2.w, acc2[i][3]);
            acc2[i][0] = fmaf(hv.w, w3.x, acc2[i][0]); acc2[i][1] = fmaf(hv.w, w3.y, acc2[i][1]);
            acc2[i][2] = fmaf(hv.w, w3.z, acc2[i][2]); acc2[i][3] = fmaf(hv.w, w3.w, acc2[i][3]);
        }
    }

    #pragma unroll
    for (int i = 0; i < 4; i++) {
        int node = nb + n0 + i;
        if (node >= NN) continue;
        float4 v = make_float4(acc2[i][0], acc2[i][1], acc2[i][2], acc2[i][3]);
        if (mode == 1) {
            v = make_float4(fmaxf(v.x, 0.f), fmaxf(v.y, 0.f), fmaxf(v.z, 0.f), fmaxf(v.w, 0.f));
        } else if (mode == 2) {
            v = make_float4(fminf(fmaxf(v.x, -10.f), 10.f), fminf(fmaxf(v.y, -10.f), 10.f),
                            fminf(fmaxf(v.z, -10.f), 10.f), fminf(fmaxf(v.w, -10.f), 10.f));
        }
        *(float4*)(out + (size_t)node * 64 + c0) = v;
    }
}

extern "C" void kernel_launch(void* const* d_in, const int* in_sizes, int n_in,
                              void* d_out, int out_size, void* d_ws, size_t ws_size,
                              hipStream_t stream)
{
    const float* x   = (const float*)d_in[0];
    const int*   ei  = (const int*)  d_in[1];
    const float* ea  = (const float*)d_in[2];
    const float* We1 = (const float*)d_in[3];
    const float* be1 = (const float*)d_in[4];
    const float* W1a = (const float*)d_in[5];
    const float* b1a = (const float*)d_in[6];
    const float* W1b = (const float*)d_in[7];
    const float* b1b = (const float*)d_in[8];
    const float* We2 = (const float*)d_in[9];
    const float* be2 = (const float*)d_in[10];
    const float* W2a = (const float*)d_in[11];
    const float* b2a = (const float*)d_in[12];
    const float* W2b = (const float*)d_in[13];
    const float* b2b = (const float*)d_in[14];
    const float* We3 = (const float*)d_in[15];
    const float* be3 = (const float*)d_in[16];
    const float* W3a = (const float*)d_in[17];
    const float* b3a = (const float*)d_in[18];
    const float* W3b = (const float*)d_in[19];
    const float* b3b = (const float*)d_in[20];

    float* out = (float*)d_out;
    float* ws = (float*)d_ws;
    // float scratch: aggr1 [12.8M] (later aliased by aggr2/aggr3), h [6.4M]
    float* aggr1 = ws;
    float* h     = ws + 12800000;
    float* aggr2 = ws;              // aliases aggr1 (dead after node_mlp<128>)
    float* aggr3 = ws + 6400000;
    // int scratch after 19.2M floats: off [NN+1], cur [NN], perm2 [2*NE]
    int* ibase = (int*)(ws + 19200000);
    int* off   = ibase;
    int* cur   = ibase + (NN + 1);
    int2* perm2 = (int2*)(ibase + (2 * NN + 2));
    // 98 block sums live in the (currently idle) aggr3 float region —
    // CSR build completes before any conv kernel touches aggr3.
    int* bsum  = (int*)(ws + 6400000);

    // ---- CSR build (shared by conv1 and conv23) ----
    hipMemsetAsync(cur, 0, (size_t)NN * sizeof(int), stream);
    hist_dst<<<2048, 256, 0, stream>>>(ei, cur);
    deg_block_sum<<<NBLK, 1024, 0, stream>>>(cur, bsum);
    scan_bsum<<<1, 128, 0, stream>>>(bsum, off);
    deg_block_scan<<<NBLK, 1024, 0, stream>>>(cur, off, bsum); // cur -> cursor
    scatter_perm<<<2048, 256, 0, stream>>>(ei, cur, perm2);

    // ---- layer 1 ----
    conv1_gather<<<(NN + 3) / 4, 256, 0, stream>>>(x, ea, We1, be1, off, perm2, aggr1);
    node_mlp<128><<<(NN + 63) / 64, 256, 0, stream>>>(x, aggr1, W1a, b1a, W1b, b1b, h, 1);

    // ---- layers 2+3 (fused edge pass) ----
    conv23_gather<<<(NN + 3) / 4, 256, 0, stream>>>(h, ea, We2, be2, We3, be3,
                                                    off, perm2, aggr2, aggr3);
    node_mlp<64><<<(NN + 63) / 64, 256, 0, stream>>>(h, aggr2, W2a, b2a, W2b, b2b, out, 0);
    node_mlp<64><<<(NN + 63) / 64, 256, 0, stream>>>(h, aggr3, W3a, b3a, W3b, b3b,
                                                     out + (size_t)NN * 64, 2);
}

// Round 5
// 1003.564 us; speedup vs baseline: 1.2706x; 1.2706x over previous
//
#include <hip/hip_runtime.h>
#include <cstddef>

#define NN 100000
#define NE 1600000
#define NBLK 98   // ceil(NN / 1024)

// ===========================================================================
// CSR build: histogram(dst) -> hierarchical exclusive scan -> scatter
// ===========================================================================
__global__ __launch_bounds__(256) void hist_dst(const int* __restrict__ ei,
                                                int* __restrict__ deg)
{
    int i = blockIdx.x * 256 + threadIdx.x;
    int stride = gridDim.x * 256;
    for (int e = i; e < NE; e += stride)
        atomicAdd(&deg[ei[NE + e]], 1);
}

__global__ __launch_bounds__(1024) void deg_block_sum(const int* __restrict__ deg,
                                                      int* __restrict__ bsum)
{
    __shared__ int s[16];
    int t = threadIdx.x;
    int i = blockIdx.x * 1024 + t;
    int v = (i < NN) ? deg[i] : 0;
    #pragma unroll
    for (int o = 32; o > 0; o >>= 1) v += __shfl_down(v, o, 64);
    if ((t & 63) == 0) s[t >> 6] = v;
    __syncthreads();
    if (t < 64) {
        int w = (t < 16) ? s[t] : 0;
        #pragma unroll
        for (int o = 8; o > 0; o >>= 1) w += __shfl_down(w, o, 64);
        if (t == 0) bsum[blockIdx.x] = w;
    }
}

__global__ __launch_bounds__(128) void scan_bsum(int* __restrict__ bsum,
                                                 int* __restrict__ off)
{
    __shared__ int s[128];
    int t = threadIdx.x;
    int v = (t < NBLK) ? bsum[t] : 0;
    s[t] = v;
    __syncthreads();
    #pragma unroll
    for (int o = 1; o < 128; o <<= 1) {
        int u = (t >= o) ? s[t - o] : 0;
        __syncthreads();
        s[t] += u;
        __syncthreads();
    }
    if (t < NBLK) bsum[t] = s[t] - v;   // exclusive block offset
    if (t == 127) off[NN] = s[127];     // grand total
}

__global__ __launch_bounds__(1024) void deg_block_scan(int* __restrict__ deg,
                                                       int* __restrict__ off,
                                                       const int* __restrict__ bsum)
{
    __shared__ int s[1024];
    int t = threadIdx.x;
    int i = blockIdx.x * 1024 + t;
    int v = (i < NN) ? deg[i] : 0;
    s[t] = v;
    __syncthreads();
    #pragma unroll
    for (int o = 1; o < 1024; o <<= 1) {
        int u = (t >= o) ? s[t - o] : 0;
        __syncthreads();
        s[t] += u;
        __syncthreads();
    }
    int excl = s[t] - v + bsum[blockIdx.x];
    if (i < NN) { off[i] = excl; deg[i] = excl; }
}

__global__ __launch_bounds__(256) void scatter_perm(const int* __restrict__ ei,
                                                    int* __restrict__ cur,
                                                    int2* __restrict__ perm2)
{
    int i = blockIdx.x * 256 + threadIdx.x;
    int stride = gridDim.x * 256;
    for (int e = i; e < NE; e += stride) {
        int s = ei[e];
        int d = ei[NE + e];
        int pos = atomicAdd(&cur[d], 1);
        perm2[pos] = make_int2(e, s);
    }
}

// readlane helper for float values (imm or SGPR lane index)
__device__ __forceinline__ float rl_f(float v, int l)
{
    return __int_as_float(__builtin_amdgcn_readlane(__float_as_int(v), l));
}

// ===========================================================================
// conv1 gather: one FULL wave per node, 2 channels/lane (128 ch).
// NO SMEM IN THE LOOP (SMEM returns out-of-order => lgkmcnt(0) drains the
// just-issued prefetches every iteration = R3's 52% stall). Instead:
//  - records: one coalesced vector load per 64 edges (perm2[base+lane])
//  - attrs: cooperative quad load - lane q*16+k loads attr k of edge q
//    (1 dword/lane, 256B unique per 4 edges, NO redundancy - R4's mistake
//    was 4KB/edge of duplicated per-lane float4 loads)
//  - broadcast attr k of edge sub to all lanes via v_readlane (imm index)
//  - x rows: per-lane float2, src row via SGPR-indexed readlane of rec.y
//  - double-buffered quads, 1-quad (4-edge ~470cy) lookahead, counted vmcnt
// aggr1[n] = sum_{e: dst=n} relu(x[src_e] + ea[e] @ We1 + be1)
// ===========================================================================
__global__ __launch_bounds__(256, 6) void conv1_gather(
    const float* __restrict__ x, const float* __restrict__ ea,
    const float* __restrict__ We, const float* __restrict__ be,
    const int* __restrict__ off, const int2* __restrict__ perm2,
    float* __restrict__ aggr)
{
    int t = threadIdx.x;
    int lane = t & 63;
    int n = blockIdx.x * 4 + (t >> 6);
    if (n >= NN) return;

    const float2* W2 = (const float2*)We;
    float2 rw[16];
    #pragma unroll
    for (int k = 0; k < 16; k++) rw[k] = W2[(k << 6) + lane];
    float2 bias = ((const float2*)be)[lane];

    int qsel = lane >> 4;        // which edge of a quad this lane loads
    int ksel = lane & 15;        // which attr within that edge

    int j0 = off[n], j1 = off[n + 1];
    float2 acc = make_float2(0.f, 0.f);

    for (int base = j0; base < j1; base += 64) {
        int cnt = min(64, j1 - base);
        int2 rec = perm2[min(base + lane, j1 - 1)];   // coalesced coop load
        int nq = (cnt + 3) >> 2;

        auto loadAttr = [&](int q) -> float {
            int ei = min(q * 4 + qsel, cnt - 1);
            int e  = __shfl(rec.x, ei);               // 1 bpermute / quad
            return ea[(size_t)(unsigned)e * 16 + ksel];
        };
        auto loadX = [&](int q, float2* xv) {
            #pragma unroll
            for (int sub = 0; sub < 4; sub++) {
                int ei = min(q * 4 + sub, cnt - 1);   // uniform
                int s  = __builtin_amdgcn_readlane(rec.y, ei);
                xv[sub] = *(const float2*)(x + (size_t)(unsigned)s * 128 + (lane << 1));
            }
        };
        auto computeQ = [&](int q, float av, const float2* xv) {
            #pragma unroll
            for (int sub = 0; sub < 4; sub++) {
                if (q * 4 + sub >= cnt) break;        // wave-uniform guard
                float2 m = bias;
                #pragma unroll
                for (int k = 0; k < 16; k++) {
                    float a = rl_f(av, sub * 16 + k); // imm readlane
                    m.x = fmaf(a, rw[k].x, m.x);
                    m.y = fmaf(a, rw[k].y, m.y);
                }
                acc.x += fmaxf(xv[sub].x + m.x, 0.f);
                acc.y += fmaxf(xv[sub].y + m.y, 0.f);
            }
        };

        // prologue: quad 0 in flight
        float avA = loadAttr(0);
        float2 xA[4]; loadX(0, xA);

        for (int q = 0; q < nq; q += 2) {
            // issue quad q+1 (set B), then compute quad q (set A)
            float avB = loadAttr(q + 1);
            float2 xB[4]; loadX(q + 1, xB);
            computeQ(q, avA, xA);
            // issue quad q+2 (set A), then compute quad q+1 (set B)
            avA = loadAttr(q + 2);
            loadX(q + 2, xA);
            if (q + 1 < nq) computeQ(q + 1, avB, xB);
        }
    }
    *(float2*)(aggr + (size_t)n * 128 + (lane << 1)) = acc;
}

// ===========================================================================
// conv_mu + conv_logstd gather, fused: one FULL wave per node. Trees split
// across the wave: lanes 0-31 = mu (W2), lanes 32-63 = logstd (W3),
// 2 channels/lane. Attrs are SHARED between the trees (same readlane
// broadcast). Same no-SMEM quad pipeline as conv1_gather.
// ===========================================================================
__global__ __launch_bounds__(256, 6) void conv23_gather(
    const float* __restrict__ h, const float* __restrict__ ea,
    const float* __restrict__ We2, const float* __restrict__ be2,
    const float* __restrict__ We3, const float* __restrict__ be3,
    const int* __restrict__ off, const int2* __restrict__ perm2,
    float* __restrict__ aggr2, float* __restrict__ aggr3)
{
    int t = threadIdx.x;
    int lane = t & 63;
    int half = lane >> 5;            // 0 = mu tree, 1 = logstd tree
    int cl = lane & 31;
    int co = cl << 1;                // channel pair within the tree
    int n = blockIdx.x * 4 + (t >> 6);
    if (n >= NN) return;

    const float2* Wp = (const float2*)(half ? We3 : We2);
    const float2* bp = (const float2*)(half ? be3 : be2);
    float2 rw[16];
    #pragma unroll
    for (int k = 0; k < 16; k++) rw[k] = Wp[(k << 5) + cl];
    float2 bias = bp[cl];

    int qsel = lane >> 4;
    int ksel = lane & 15;

    int j0 = off[n], j1 = off[n + 1];
    float2 acc = make_float2(0.f, 0.f);

    for (int base = j0; base < j1; base += 64) {
        int cnt = min(64, j1 - base);
        int2 rec = perm2[min(base + lane, j1 - 1)];
        int nq = (cnt + 3) >> 2;

        auto loadAttr = [&](int q) -> float {
            int ei = min(q * 4 + qsel, cnt - 1);
            int e  = __shfl(rec.x, ei);
            return ea[(size_t)(unsigned)e * 16 + ksel];
        };
        auto loadH = [&](int q, float2* hv) {
            #pragma unroll
            for (int sub = 0; sub < 4; sub++) {
                int ei = min(q * 4 + sub, cnt - 1);
                int s  = __builtin_amdgcn_readlane(rec.y, ei);
                hv[sub] = *(const float2*)(h + (size_t)(unsigned)s * 64 + co);
            }
        };
        auto computeQ = [&](int q, float av, const float2* hv) {
            #pragma unroll
            for (int sub = 0; sub < 4; sub++) {
                if (q * 4 + sub >= cnt) break;
                float2 m = bias;
                #pragma unroll
                for (int k = 0; k < 16; k++) {
                    float a = rl_f(av, sub * 16 + k);
                    m.x = fmaf(a, rw[k].x, m.x);
                    m.y = fmaf(a, rw[k].y, m.y);
                }
                acc.x += fmaxf(hv[sub].x + m.x, 0.f);
                acc.y += fmaxf(hv[sub].y + m.y, 0.f);
            }
        };

        float avA = loadAttr(0);
        float2 hA[4]; loadH(0, hA);

        for (int q = 0; q < nq; q += 2) {
            float avB = loadAttr(q + 1);
            float2 hB[4]; loadH(q + 1, hB);
            computeQ(q, avA, hA);
            avA = loadAttr(q + 2);
            loadH(q + 2, hA);
            if (q + 1 < nq) computeQ(q + 1, avB, hB);
        }
    }
    float* dstp = (half ? aggr3 : aggr2) + (size_t)n * 64 + co;
    *(float2*)dstp = acc;
}

// ===========================================================================
// Node MLP: out = epilogue( relu((xin+aggr) @ Wa + ba) @ Wb + bb )
// KIN -> 64 -> 64. 64 nodes per block, 256 threads, 4x4 register tiles.
// mode: 0 = none, 1 = relu, 2 = clip(-10, 10)
// ===========================================================================
template <int KIN>
__global__ __launch_bounds__(256) void node_mlp(
    const float* __restrict__ xin, const float* __restrict__ aggr,
    const float* __restrict__ Wa, const float* __restrict__ ba,
    const float* __restrict__ Wb, const float* __restrict__ bb,
    float* __restrict__ out, int mode)
{
    constexpr int S0 = KIN + 4;
    constexpr int K4 = KIN / 4;
    __shared__ float sWa[KIN * 64];
    __shared__ float sWb[64 * 64];
    __shared__ float sh[64 * S0];
    __shared__ float sba[64], sbb[64];
    int t = threadIdx.x;
    for (int i = t; i < KIN * 16; i += 256) ((float4*)sWa)[i] = ((const float4*)Wa)[i];
    for (int i = t; i < 1024; i += 256)     ((float4*)sWb)[i] = ((const float4*)Wb)[i];
    if (t < 64) { sba[t] = ba[t]; sbb[t] = bb[t]; }

    int nb = blockIdx.x << 6;
    for (int i = t; i < 64 * K4; i += 256) {
        int n = i / K4, k4 = i % K4;
        int node = nb + n;
        float4 v = make_float4(0.f, 0.f, 0.f, 0.f);
        if (node < NN) {
            float4 a = ((const float4*)(xin  + (size_t)node * KIN))[k4];
            float4 b = ((const float4*)(aggr + (size_t)node * KIN))[k4];
            v = make_float4(a.x + b.x, a.y + b.y, a.z + b.z, a.w + b.w);
        }
        *(float4*)&sh[n * S0 + (k4 << 2)] = v;
    }
    __syncthreads();

    int tx = t & 15, ty = t >> 4;
    int c0 = tx << 2, n0 = ty << 2;

    float4 b1 = *(const float4*)&sba[c0];
    float acc[4][4];
    #pragma unroll
    for (int i = 0; i < 4; i++) { acc[i][0] = b1.x; acc[i][1] = b1.y; acc[i][2] = b1.z; acc[i][3] = b1.w; }
    for (int k4 = 0; k4 < K4; k4++) {
        int k = k4 << 2;
        float4 w0 = *(const float4*)&sWa[((k + 0) << 6) + c0];
        float4 w1 = *(const float4*)&sWa[((k + 1) << 6) + c0];
        float4 w2 = *(const float4*)&sWa[((k + 2) << 6) + c0];
        float4 w3 = *(const float4*)&sWa[((k + 3) << 6) + c0];
        #pragma unroll
        for (int i = 0; i < 4; i++) {
            float4 hv = *(const float4*)&sh[(n0 + i) * S0 + k];
            acc[i][0] = fmaf(hv.x, w0.x, acc[i][0]); acc[i][1] = fmaf(hv.x, w0.y, acc[i][1]);
            acc[i][2] = fmaf(hv.x, w0.z, acc[i][2]); acc[i][3] = fmaf(hv.x, w0.w, acc[i][3]);
            acc[i][0] = fmaf(hv.y, w1.x, acc[i][0]); acc[i][1] = fmaf(hv.y, w1.y, acc[i][1]);
            acc[i][2] = fmaf(hv.y, w1.z, acc[i][2]); acc[i][3] = fmaf(hv.y, w1.w, acc[i][3]);
            acc[i][0] = fmaf(hv.z, w2.x, acc[i][0]); acc[i][1] = fmaf(hv.z, w2.y, acc[i][1]);
            acc[i][2] = fmaf(hv.z, w2.z, acc[i][2]); acc[i][3] = fmaf(hv.z, w2.w, acc[i][3]);
            acc[i][0] = fmaf(hv.w, w3.x, acc[i][0]); acc[i][1] = fmaf(hv.w, w3.y, acc[i][1]);
            acc[i][2] = fmaf(hv.w, w3.z, acc[i][2]); acc[i][3] = fmaf(hv.w, w3.w, acc[i][3]);
        }
    }
    __syncthreads();
    #pragma unroll
    for (int i = 0; i < 4; i++) {
        float4 v = make_float4(fmaxf(acc[i][0], 0.f), fmaxf(acc[i][1], 0.f),
                               fmaxf(acc[i][2], 0.f), fmaxf(acc[i][3], 0.f));
        *(float4*)&sh[(n0 + i) * 68 + c0] = v;
    }
    __syncthreads();

    float4 b2 = *(const float4*)&sbb[c0];
    float acc2[4][4];
    #pragma unroll
    for (int i = 0; i < 4; i++) { acc2[i][0] = b2.x; acc2[i][1] = b2.y; acc2[i][2] = b2.z; acc2[i][3] = b2.w; }
    for (int k4 = 0; k4 < 16; k4++) {
        int k = k4 << 2;
        float4 w0 = *(const float4*)&sWb[((k + 0) << 6) + c0];
        float4 w1 = *(const float4*)&sWb[((k + 1) << 6) + c0];
        float4 w2 = *(const float4*)&sWb[((k + 2) << 6) + c0];
        float4 w3 = *(const float4*)&sWb[((k + 3) << 6) + c0];
        #pragma unroll
        for (int i = 0; i < 4; i++) {
            float4 hv = *(const float4*)&sh[(n0 + i) * 68 + k];
            acc2[i][0] = fmaf(hv.x, w0.x, acc2[i][0]); acc2[i][1] = fmaf(hv.x, w0.y, acc2[i][1]);
            acc2[i][2] = fmaf(hv.x, w0.z, acc2[i][2]); acc2[i][3] = fmaf(hv.x, w0.w, acc2[i][3]);
            acc2[i][0] = fmaf(hv.y, w1.x, acc2[i][0]); acc2[i][1] = fmaf(hv.y, w1.y, acc2[i][1]);
            acc2[i][2] = fmaf(hv.y, w1.z, acc2[i][2]); acc2[i][3] = fmaf(hv.y, w1.w, acc2[i][3]);
            acc2[i][0] = fmaf(hv.z, w2.x, acc2[i][0]); acc2[i][1] = fmaf(hv.z, w2.y, acc2[i][1]);
            acc2[i][2] = fmaf(hv.z, w2.z, acc2[i][2]); acc2[i][3] = fmaf(hv.z, w2.w, acc2[i][3]);
            acc2[i][0] = fmaf(hv.w, w3.x, acc2[i][0]); acc2[i][1] = fmaf(hv.w, w3.y, acc2[i][1]);
            acc2[i][2] = fmaf(hv.w, w3.z, acc2[i][2]); acc2[i][3] = fmaf(hv.w, w3.w, acc2[i][3]);
        }
    }

    #pragma unroll
    for (int i = 0; i < 4; i++) {
        int node = nb + n0 + i;
        if (node >= NN) continue;
        float4 v = make_float4(acc2[i][0], acc2[i][1], acc2[i][2], acc2[i][3]);
        if (mode == 1) {
            v = make_float4(fmaxf(v.x, 0.f), fmaxf(v.y, 0.f), fmaxf(v.z, 0.f), fmaxf(v.w, 0.f));
        } else if (mode == 2) {
            v = make_float4(fminf(fmaxf(v.x, -10.f), 10.f), fminf(fmaxf(v.y, -10.f), 10.f),
                            fminf(fmaxf(v.z, -10.f), 10.f), fminf(fmaxf(v.w, -10.f), 10.f));
        }
        *(float4*)(out + (size_t)node * 64 + c0) = v;
    }
}

extern "C" void kernel_launch(void* const* d_in, const int* in_sizes, int n_in,
                              void* d_out, int out_size, void* d_ws, size_t ws_size,
                              hipStream_t stream)
{
    const float* x   = (const float*)d_in[0];
    const int*   ei  = (const int*)  d_in[1];
    const float* ea  = (const float*)d_in[2];
    const float* We1 = (const float*)d_in[3];
    const float* be1 = (const float*)d_in[4];
    const float* W1a = (const float*)d_in[5];
    const float* b1a = (const float*)d_in[6];
    const float* W1b = (const float*)d_in[7];
    const float* b1b = (const float*)d_in[8];
    const float* We2 = (const float*)d_in[9];
    const float* be2 = (const float*)d_in[10];
    const float* W2a = (const float*)d_in[11];
    const float* b2a = (const float*)d_in[12];
    const float* W2b = (const float*)d_in[13];
    const float* b2b = (const float*)d_in[14];
    const float* We3 = (const float*)d_in[15];
    const float* be3 = (const float*)d_in[16];
    const float* W3a = (const float*)d_in[17];
    const float* b3a = (const float*)d_in[18];
    const float* W3b = (const float*)d_in[19];
    const float* b3b = (const float*)d_in[20];

    float* out = (float*)d_out;
    float* ws = (float*)d_ws;
    // float scratch: aggr1 [12.8M] (later aliased by aggr2/aggr3), h [6.4M]
    float* aggr1 = ws;
    float* h     = ws + 12800000;
    float* aggr2 = ws;              // aliases aggr1 (dead after node_mlp<128>)
    float* aggr3 = ws + 6400000;
    // int scratch after 19.2M floats: off [NN+1], cur [NN], perm2 [2*NE]
    int* ibase = (int*)(ws + 19200000);
    int* off   = ibase;
    int* cur   = ibase + (NN + 1);
    int2* perm2 = (int2*)(ibase + (2 * NN + 2));
    // 98 block sums live in the (currently idle) aggr3 float region —
    // CSR build completes before any conv kernel touches aggr3.
    int* bsum  = (int*)(ws + 6400000);

    // ---- CSR build (shared by conv1 and conv23) ----
    hipMemsetAsync(cur, 0, (size_t)NN * sizeof(int), stream);
    hist_dst<<<2048, 256, 0, stream>>>(ei, cur);
    deg_block_sum<<<NBLK, 1024, 0, stream>>>(cur, bsum);
    scan_bsum<<<1, 128, 0, stream>>>(bsum, off);
    deg_block_scan<<<NBLK, 1024, 0, stream>>>(cur, off, bsum); // cur -> cursor
    scatter_perm<<<2048, 256, 0, stream>>>(ei, cur, perm2);

    // ---- layer 1 ----
    conv1_gather<<<(NN + 3) / 4, 256, 0, stream>>>(x, ea, We1, be1, off, perm2, aggr1);
    node_mlp<128><<<(NN + 63) / 64, 256, 0, stream>>>(x, aggr1, W1a, b1a, W1b, b1b, h, 1);

    // ---- layers 2+3 (fused edge pass) ----
    conv23_gather<<<(NN + 3) / 4, 256, 0, stream>>>(h, ea, We2, be2, We3, be3,
                                                    off, perm2, aggr2, aggr3);
    node_mlp<64><<<(NN + 63) / 64, 256, 0, stream>>>(h, aggr2, W2a, b2a, W2b, b2b, out, 0);
    node_mlp<64><<<(NN + 63) / 64, 256, 0, stream>>>(h, aggr3, W3a, b3a, W3b, b3b,
                                                     out + (size_t)NN * 64, 2);
}